// Round 1
// baseline (30741.803 us; speedup 1.0000x reference)
//
#include <hip/hip_runtime.h>
#include <math.h>

// Problem constants
#define RNN_B 64
#define RNN_T 512
#define RNN_IN 512
#define RNN_H 1024

// ws layout (float offsets):
//   0       h0buf[0]   (H*B = 65536 floats)
//   65536   h1buf[0]
//   131072  h0buf[1]   <- zeroed each launch (initial h0_{-1})
//   196608  h1buf[1]   <- zeroed each launch (initial h1_{-1})
//   262144  barrier: [0]=count, [1]=generation (zeroed each launch)
// total needed: 262160 floats ~= 1.05 MB

__device__ __forceinline__ void fma16(float4 acc[4], const float4 w, const float4 h) {
  acc[0].x = fmaf(w.x, h.x, acc[0].x); acc[0].y = fmaf(w.x, h.y, acc[0].y);
  acc[0].z = fmaf(w.x, h.z, acc[0].z); acc[0].w = fmaf(w.x, h.w, acc[0].w);
  acc[1].x = fmaf(w.y, h.x, acc[1].x); acc[1].y = fmaf(w.y, h.y, acc[1].y);
  acc[1].z = fmaf(w.y, h.z, acc[1].z); acc[1].w = fmaf(w.y, h.w, acc[1].w);
  acc[2].x = fmaf(w.z, h.x, acc[2].x); acc[2].y = fmaf(w.z, h.y, acc[2].y);
  acc[2].z = fmaf(w.z, h.z, acc[2].z); acc[2].w = fmaf(w.z, h.w, acc[2].w);
  acc[3].x = fmaf(w.w, h.x, acc[3].x); acc[3].y = fmaf(w.w, h.y, acc[3].y);
  acc[3].z = fmaf(w.w, h.z, acc[3].z); acc[3].w = fmaf(w.w, h.w, acc[3].w);
}

// butterfly sum over lane bits 0..4 (the 32-way K split)
__device__ __forceinline__ void reduce32(float4 acc[4]) {
  #pragma unroll
  for (int m = 1; m <= 16; m <<= 1) {
    #pragma unroll
    for (int c = 0; c < 4; ++c) {
      acc[c].x += __shfl_xor(acc[c].x, m, 64);
      acc[c].y += __shfl_xor(acc[c].y, m, 64);
      acc[c].z += __shfl_xor(acc[c].z, m, 64);
      acc[c].w += __shfl_xor(acc[c].w, m, 64);
    }
  }
}

// Sense-free monotonic-generation grid barrier. bar[0]=arrive count, bar[1]=gen.
// Device-scope atomics/fences per G16 (cross-XCD L2 non-coherence).
__device__ __forceinline__ void grid_barrier(unsigned* bar, unsigned target) {
  __syncthreads();
  if (threadIdx.x == 0) {
    __threadfence();  // release my block's global stores (agent scope)
    unsigned old = __hip_atomic_fetch_add(bar, 1u, __ATOMIC_ACQ_REL, __HIP_MEMORY_SCOPE_AGENT);
    if (old == (unsigned)(gridDim.x - 1)) {
      __hip_atomic_store(bar, 0u, __ATOMIC_RELAXED, __HIP_MEMORY_SCOPE_AGENT);
      __hip_atomic_store(bar + 1, target, __ATOMIC_RELEASE, __HIP_MEMORY_SCOPE_AGENT);
    } else {
      while (__hip_atomic_load(bar + 1, __ATOMIC_ACQUIRE, __HIP_MEMORY_SCOPE_AGENT) < target) {
        __builtin_amdgcn_s_sleep(1);
      }
    }
  }
  __syncthreads();
}

// ---------------------------------------------------------------------------
// Precompute: out[b][t][n] = x[b,t,:]·W_ih0[n,:] + b_ih0[n] + b_hh0[n]
// Written into the outputs region of d_out; consumed at phase t, overwritten
// by h1_t at phase t+1 (strictly later) -> no lifetime conflict.
// grid (16 n-tiles, 512 t), 256 threads. 64n x 64b tile, K=512 in 64-chunks.
// ---------------------------------------------------------------------------
__global__ __launch_bounds__(256) void pre_kernel(
    const float* __restrict__ x, const float* __restrict__ Wih0,
    const float* __restrict__ bih0, const float* __restrict__ bhh0,
    float* __restrict__ out)
{
  __shared__ float xs[64][68];  // [k][b], +4 pad keeps float4 alignment
  __shared__ float wl[64][68];  // [k][n]
  const int t  = blockIdx.y;
  const int n0 = blockIdx.x * 64;
  const int tid = threadIdx.x;
  const int tx = tid & 15;   // b-quad
  const int ty = tid >> 4;   // n-quad
  const int kf4 = tid & 15;  // staging: k float4 index
  const int row = tid >> 4;  // staging: row group

  float4 acc[4];
  acc[0] = acc[1] = acc[2] = acc[3] = make_float4(0.f, 0.f, 0.f, 0.f);

  for (int k0 = 0; k0 < RNN_IN; k0 += 64) {
    #pragma unroll
    for (int r = 0; r < 4; ++r) {
      const int rr = row + 16 * r;
      float4 v = *(const float4*)(x + ((size_t)rr * RNN_T + t) * RNN_IN + k0 + kf4 * 4);
      xs[kf4*4+0][rr] = v.x; xs[kf4*4+1][rr] = v.y;
      xs[kf4*4+2][rr] = v.z; xs[kf4*4+3][rr] = v.w;
      float4 w = *(const float4*)(Wih0 + (size_t)(n0 + rr) * RNN_IN + k0 + kf4 * 4);
      wl[kf4*4+0][rr] = w.x; wl[kf4*4+1][rr] = w.y;
      wl[kf4*4+2][rr] = w.z; wl[kf4*4+3][rr] = w.w;
    }
    __syncthreads();
    #pragma unroll 8
    for (int k = 0; k < 64; ++k) {
      float4 xv = *(const float4*)&xs[k][tx * 4];
      float4 wv = *(const float4*)&wl[k][ty * 4];
      fma16(acc, wv, xv);
    }
    __syncthreads();
  }

  // add bias, transpose acc (f4-over-b) -> n-contiguous rows via LDS
  #pragma unroll
  for (int i = 0; i < 4; ++i) {
    const int n = n0 + ty * 4 + i;
    const float bi = bih0[n] + bhh0[n];
    xs[ty*4+i][tx*4+0] = acc[i].x + bi;
    xs[ty*4+i][tx*4+1] = acc[i].y + bi;
    xs[ty*4+i][tx*4+2] = acc[i].z + bi;
    xs[ty*4+i][tx*4+3] = acc[i].w + bi;
  }
  __syncthreads();
  #pragma unroll
  for (int rep = 0; rep < 4; ++rep) {
    const int idx = tid + 256 * rep;   // 0..1023 = 16 n-quads x 64 b
    const int q = idx & 15;
    const int b = idx >> 4;
    float4 o;
    o.x = xs[q*4+0][b]; o.y = xs[q*4+1][b]; o.z = xs[q*4+2][b]; o.w = xs[q*4+3][b];
    *(float4*)(out + ((size_t)b * RNN_T + t) * RNN_H + n0 + q * 4) = o;
  }
}

// ---------------------------------------------------------------------------
// Persistent recurrence kernel (cooperative, 256 blocks x 512 threads).
// Block owns columns n0..n0+3 of both h0 and h1; weight rows live in LDS.
// Phase p: compute h0_p (layer0) and h1_{p-1} (layer1); one grid barrier.
// h state layout: [n][b] (f4 over b). 513 phases total.
// ---------------------------------------------------------------------------
__global__ __launch_bounds__(512, 1) void rnn_kernel(
    const float* __restrict__ Whh0, const float* __restrict__ Wih1,
    const float* __restrict__ Whh1, const float* __restrict__ bih1,
    const float* __restrict__ bhh1, float* __restrict__ out,
    float* __restrict__ hws)
{
  __shared__ float w0[RNN_H * 4];      // [k][4n] Whh0 rows, 16 KB
  __shared__ float w1[RNN_H * 8];      // [k][4n] Wih1 rows then Whh1 rows, 32 KB
  __shared__ float tile[4 * RNN_B];    // out-transpose staging, 1 KB

  const int tid = threadIdx.x;
  const int n0 = blockIdx.x * 4;

  // stage this block's weight rows into LDS (once)
  for (int nl = 0; nl < 4; ++nl) {
    const float* s0 = Whh0 + (size_t)(n0 + nl) * RNN_H;
    const float* s1 = Wih1 + (size_t)(n0 + nl) * RNN_H;
    const float* s2 = Whh1 + (size_t)(n0 + nl) * RNN_H;
    for (int k = tid; k < RNN_H; k += 512) {
      w0[k * 4 + nl] = s0[k];
      w1[k * 4 + nl] = s1[k];
      w1[(RNN_H + k) * 4 + nl] = s2[k];
    }
  }
  float bias[4];
  #pragma unroll
  for (int nl = 0; nl < 4; ++nl) bias[nl] = bih1[n0 + nl] + bhh1[n0 + nl];
  __syncthreads();

  const int kq = tid & 31;        // 32-way K split (lane bits 0..4)
  const int bq = tid >> 5;        // 16 b-quads
  const int b4 = bq * 4;

  unsigned* bar = (unsigned*)(hws + 262144);
  float* h0buf[2] = { hws,         hws + 131072 };
  float* h1buf[2] = { hws + 65536, hws + 196608 };

  for (int p = 0; p <= RNN_T; ++p) {
    // ---- layer 0: h0_p = tanh(pre[:,p,:] + h0_{p-1} @ Whh0^T) ----
    if (p < RNN_T) {
      const float* hp = h0buf[(p + 1) & 1] + (size_t)kq * RNN_B + b4;
      float* h0c = h0buf[p & 1];
      float4 acc[4];
      acc[0] = acc[1] = acc[2] = acc[3] = make_float4(0.f, 0.f, 0.f, 0.f);
      const float* wp = w0 + kq * 4;
      #pragma unroll 8
      for (int j = 0; j < 32; ++j) {               // k = kq + 32*j
        float4 hv = *(const float4*)(hp + (size_t)j * 32 * RNN_B);
        float4 wv = *(const float4*)(wp + j * 32 * 4);
        fma16(acc, wv, hv);
      }
      reduce32(acc);
      if (kq == 0) {
        #pragma unroll
        for (int nl = 0; nl < 4; ++nl) {
          const int n = n0 + nl;
          float4 v;
          v.x = tanhf(acc[nl].x + out[((size_t)(b4+0) * RNN_T + p) * RNN_H + n]);
          v.y = tanhf(acc[nl].y + out[((size_t)(b4+1) * RNN_T + p) * RNN_H + n]);
          v.z = tanhf(acc[nl].z + out[((size_t)(b4+2) * RNN_T + p) * RNN_H + n]);
          v.w = tanhf(acc[nl].w + out[((size_t)(b4+3) * RNN_T + p) * RNN_H + n]);
          *(float4*)(h0c + (size_t)n * RNN_B + b4) = v;
        }
      }
    }
    // ---- layer 1: h1_t = tanh(h0_t @ Wih1^T + h1_{t-1} @ Whh1^T + bias), t=p-1 ----
    if (p >= 1) {
      const int t = p - 1;
      const float* h0t = h0buf[t & 1]       + (size_t)kq * RNN_B + b4;
      const float* h1p = h1buf[(t + 1) & 1] + (size_t)kq * RNN_B + b4;
      float* h1c = h1buf[t & 1];
      float4 acc[4];
      acc[0] = acc[1] = acc[2] = acc[3] = make_float4(0.f, 0.f, 0.f, 0.f);
      const float* wpa = w1 + kq * 4;
      const float* wpb = w1 + RNN_H * 4 + kq * 4;
      #pragma unroll 8
      for (int j = 0; j < 32; ++j) {
        float4 hv = *(const float4*)(h0t + (size_t)j * 32 * RNN_B);
        float4 wv = *(const float4*)(wpa + j * 32 * 4);
        fma16(acc, wv, hv);
      }
      #pragma unroll 8
      for (int j = 0; j < 32; ++j) {
        float4 hv = *(const float4*)(h1p + (size_t)j * 32 * RNN_B);
        float4 wv = *(const float4*)(wpb + j * 32 * 4);
        fma16(acc, wv, hv);
      }
      reduce32(acc);
      if (kq == 0) {
        #pragma unroll
        for (int nl = 0; nl < 4; ++nl) {
          float4 v;
          v.x = tanhf(acc[nl].x + bias[nl]);
          v.y = tanhf(acc[nl].y + bias[nl]);
          v.z = tanhf(acc[nl].z + bias[nl]);
          v.w = tanhf(acc[nl].w + bias[nl]);
          *(float4*)(h1c + (size_t)(n0 + nl) * RNN_B + b4) = v;
          tile[nl * RNN_B + b4 + 0] = v.x;
          tile[nl * RNN_B + b4 + 1] = v.y;
          tile[nl * RNN_B + b4 + 2] = v.z;
          tile[nl * RNN_B + b4 + 3] = v.w;
        }
      }
      __syncthreads();
      if (tid < RNN_B) {  // write out[b][t][n0..n0+3] as float4
        float4 o;
        o.x = tile[0 * RNN_B + tid]; o.y = tile[1 * RNN_B + tid];
        o.z = tile[2 * RNN_B + tid]; o.w = tile[3 * RNN_B + tid];
        *(float4*)(out + ((size_t)tid * RNN_T + t) * RNN_H + n0) = o;
      }
    }
    grid_barrier(bar, (unsigned)(p + 1));
  }

  // h_final tail: out[BTH + l*B*H + b*H + n] ; finals live in buf index 1
  {
    const int l  = tid >> 8;        // 0..1
    const int b  = (tid >> 2) & 63;
    const int nl = tid & 3;
    const float* hf = (l == 0) ? (hws + 131072) : (hws + 196608);
    out[(size_t)RNN_B * RNN_T * RNN_H + ((size_t)l * RNN_B + b) * RNN_H + n0 + nl]
        = hf[(size_t)(n0 + nl) * RNN_B + b];
  }
}

extern "C" void kernel_launch(void* const* d_in, const int* in_sizes, int n_in,
                              void* d_out, int out_size, void* d_ws, size_t ws_size,
                              hipStream_t stream) {
  (void)in_sizes; (void)n_in; (void)out_size; (void)ws_size;
  const float* x    = (const float*)d_in[0];
  const float* Wih0 = (const float*)d_in[1];
  const float* Whh0 = (const float*)d_in[2];
  const float* bih0 = (const float*)d_in[3];
  const float* bhh0 = (const float*)d_in[4];
  const float* Wih1 = (const float*)d_in[5];
  const float* Whh1 = (const float*)d_in[6];
  const float* bih1 = (const float*)d_in[7];
  const float* bhh1 = (const float*)d_in[8];
  float* out = (float*)d_out;
  float* hws = (float*)d_ws;

  // zero initial h buffers (index 1) + barrier words (ws is 0xAA-poisoned)
  hipMemsetAsync(hws + 131072, 0, (131072 + 16) * sizeof(float), stream);

  dim3 pg(16, 512);
  pre_kernel<<<pg, 256, 0, stream>>>(x, Wih0, bih0, bhh0, out);

  void* args[] = { (void*)&Whh0, (void*)&Wih1, (void*)&Whh1,
                   (void*)&bih1, (void*)&bhh1, (void*)&out, (void*)&hws };
  hipLaunchCooperativeKernel((const void*)rnn_kernel, dim3(256), dim3(512),
                             args, 0, stream);
}